// Round 1
// baseline (190.788 us; speedup 1.0000x reference)
//
#include <hip/hip_runtime.h>
#include <stdint.h>

#define LMAX 8

struct __align__(16) PK { unsigned long long key; float logp; int len; };

// K1: pack pieces into 64-bit keys, pack sequence windows, zero M.
__global__ void k_prep(const int* __restrict__ seq, const int* __restrict__ pieces,
                       const int* __restrict__ plens, const float* __restrict__ logp,
                       PK* __restrict__ pk, unsigned long long* __restrict__ w64,
                       float* __restrict__ M, int T, int V) {
  int idx = blockIdx.x * blockDim.x + threadIdx.x;
  if (idx < V) {
    const int* pr = pieces + idx * LMAX;
    int len = plens[idx];
    unsigned long long key = 0ull;
    #pragma unroll
    for (int l = 0; l < LMAX; ++l) {
      unsigned long long b = (unsigned long long)(pr[l] & 0xFF);
      if (l < len) key |= b << (8 * l);
    }
    PK o; o.key = key; o.logp = logp[idx]; o.len = len;
    pk[idx] = o;
  } else if (idx < V + T) {
    int t = idx - V;
    unsigned long long w = 0ull;
    #pragma unroll
    for (int l = 0; l < LMAX; ++l) {
      int pos = t + l;
      unsigned long long b = (pos < T) ? (unsigned long long)(seq[pos] & 0xFF) : 0xFFull;
      w |= b << (8 * l);
    }
    w64[t] = w;
  } else if (idx < V + T + T * LMAX) {
    M[idx - V - T] = 0.f;
  }
}

// K2: M[t][len-1] += p_v for every matching (t,v). Matches are rare (~17/t),
// so global float atomics are essentially free.
__global__ void k_match(const PK* __restrict__ pk, const unsigned long long* __restrict__ w64,
                        float* __restrict__ M, int T, int V, int tPer) {
  int v = blockIdx.x * blockDim.x + threadIdx.x;
  PK p = pk[v];
  unsigned long long mask = (p.len >= 8) ? ~0ull : ((1ull << (8 * p.len)) - 1ull);
  unsigned long long key = p.key;
  int t0 = blockIdx.y * tPer;
  float prob = -1.f;
  for (int t = t0; t < t0 + tPer; ++t) {
    unsigned long long w = w64[t];
    if (((w ^ key) & mask) == 0ull) {
      if (prob < 0.f) prob = expf(p.logp);
      atomicAdd(&M[t * LMAX + (p.len - 1)], prob);
    }
  }
}

// K3: serial order-8 scans (alpha push-form, beta pull-form) in scaled fp64
// probability domain. Block 0 = alpha, block 1 = beta. 8-step unroll keeps all
// ring indices compile-time constants (registers, not scratch).
__global__ __launch_bounds__(256) void k_scan(const float* __restrict__ M,
        double* __restrict__ aD, int* __restrict__ cntA,
        double* __restrict__ bD, int* __restrict__ cntB,
        float* __restrict__ aL, float* __restrict__ bL, int T) {
  extern __shared__ __align__(16) float sM[];
  int tid = threadIdx.x;
  const float4* src = (const float4*)M;
  float4* dst = (float4*)sM;
  int n4 = T * LMAX / 4;
  for (int i = tid; i < n4; i += 256) dst[i] = src[i];
  __syncthreads();
  const double SC = 1e100;
  const double THR = 1e-100;
  const double LN_SC = 230.25850929940457;  // ln(1e100)
  if (blockIdx.x == 0) {
    if (tid == 0) {
      double f[8] = {0,0,0,0,0,0,0,0};
      double a = 1.0;
      int cnt = 0;
      aD[0] = 1.0; cntA[0] = 0;
      for (int s0 = 0; s0 < T; s0 += 8) {
        float4 rows[16];
        #pragma unroll
        for (int i = 0; i < 16; ++i) rows[i] = *(const float4*)&sM[s0 * 8 + i * 4];
        #pragma unroll
        for (int k = 0; k < 8; ++k) {
          const float4 r0 = rows[2 * k], r1 = rows[2 * k + 1];
          f[(k + 1) & 7] += a * (double)r0.x;
          f[(k + 2) & 7] += a * (double)r0.y;
          f[(k + 3) & 7] += a * (double)r0.z;
          f[(k + 4) & 7] += a * (double)r0.w;
          f[(k + 5) & 7] += a * (double)r1.x;
          f[(k + 6) & 7] += a * (double)r1.y;
          f[(k + 7) & 7] += a * (double)r1.z;
          f[(k + 0) & 7] += a * (double)r1.w;  // l=8 -> slot (k+8)&7
          double an = f[(k + 1) & 7];
          f[(k + 1) & 7] = 0.0;
          a = an;
          aD[s0 + k + 1] = a; cntA[s0 + k + 1] = cnt;
        }
        if (a < THR) {  // per-step shrink >= ~1.7e-6 (single-char path) -> safe in fp64
          a *= SC;
          #pragma unroll
          for (int i = 0; i < 8; ++i) f[i] *= SC;
          cnt++;
        }
      }
    }
    __syncthreads();
    for (int i = tid; i <= T; i += 256)
      aL[i] = (float)(log(aD[i]) - (double)cntA[i] * LN_SC);
  } else {
    if (tid == 0) {
      double r[8] = {0,0,0,0,0,0,0,0};
      r[0] = 1.0;  // b[T]=1; requires T % 8 == 0 (T=2048)
      bD[T] = 1.0; cntB[T] = 0;
      int cnt = 0;
      for (int t0 = T - 8; t0 >= 0; t0 -= 8) {
        float4 rows[16];
        #pragma unroll
        for (int i = 0; i < 16; ++i) rows[i] = *(const float4*)&sM[t0 * 8 + i * 4];
        #pragma unroll
        for (int k = 7; k >= 0; --k) {
          const float4 r0 = rows[2 * k], r1 = rows[2 * k + 1];
          double p0 = (double)r0.x * r[(k + 1) & 7];
          double p1 = (double)r0.y * r[(k + 2) & 7];
          double p2 = (double)r0.z * r[(k + 3) & 7];
          double p3 = (double)r0.w * r[(k + 4) & 7];
          double p4 = (double)r1.x * r[(k + 5) & 7];
          double p5 = (double)r1.y * r[(k + 6) & 7];
          double p6 = (double)r1.z * r[(k + 7) & 7];
          double p7 = (double)r1.w * r[(k + 0) & 7];
          double b = ((p0 + p1) + (p2 + p3)) + ((p4 + p5) + (p6 + p7));
          bD[t0 + k] = b; cntB[t0 + k] = cnt;
          r[k & 7] = b;
        }
        double g = r[0];  // b[t0]
        if (g < THR) {
          #pragma unroll
          for (int i = 0; i < 8; ++i) r[i] *= SC;
          cnt++;
        }
      }
    }
    __syncthreads();
    for (int i = tid; i <= T; i += 256)
      bL[i] = (float)(log(bD[i]) - (double)cntB[i] * LN_SC);
  }
}

// K4: dense output. Thread owns one v, loops over a t-chunk; PK stays in
// registers, w64[t]/aL[t] are wave-uniform (L1 broadcast), stores coalesced.
__global__ void k_out(const PK* __restrict__ pk, const unsigned long long* __restrict__ w64,
                      const float* __restrict__ aL, const float* __restrict__ bL,
                      float* __restrict__ out, int T, int V, int tPer) {
  int v = blockIdx.x * blockDim.x + threadIdx.x;
  PK p = pk[v];
  unsigned long long mask = (p.len >= 8) ? ~0ull : ((1ull << (8 * p.len)) - 1ull);
  unsigned long long key = p.key;
  float norm = aL[T];
  float base = p.logp - norm;
  int t0 = blockIdx.y * tPer;
  for (int t = t0; t < t0 + tPer; ++t) {
    unsigned long long w = w64[t];
    float val = 0.f;
    if (((w ^ key) & mask) == 0ull)
      val = __expf(aL[t] + base + bL[t + p.len]);
    out[(size_t)t * V + v] = val;
  }
}

extern "C" void kernel_launch(void* const* d_in, const int* in_sizes, int n_in,
                              void* d_out, int out_size, void* d_ws, size_t ws_size,
                              hipStream_t stream) {
  const int* seq    = (const int*)d_in[0];
  const int* pieces = (const int*)d_in[1];
  const int* plens  = (const int*)d_in[2];
  const float* logp = (const float*)d_in[3];
  float* out = (float*)d_out;
  const int T = in_sizes[0];
  const int V = in_sizes[2];

  char* p = (char*)d_ws;
  PK* pk = (PK*)p;                     p += (size_t)V * sizeof(PK);
  unsigned long long* w64 = (unsigned long long*)p; p += (size_t)T * 8;
  float* M = (float*)p;                p += (size_t)T * LMAX * 4;
  double* aD = (double*)p;             p += (size_t)(T + 1) * 8;
  double* bD = (double*)p;             p += (size_t)(T + 1) * 8;
  int* cntA = (int*)p;                 p += (size_t)(T + 1) * 4;
  int* cntB = (int*)p;                 p += (size_t)(T + 1) * 4;
  float* aL = (float*)p;               p += (size_t)(T + 1) * 4;
  float* bL = (float*)p;               p += (size_t)(T + 1) * 4;

  int prepN = V + T + T * LMAX;
  k_prep<<<(prepN + 255) / 256, 256, 0, stream>>>(seq, pieces, plens, logp, pk, w64, M, T, V);

  const int tPer2 = 128;
  dim3 g2(V / 256, T / tPer2);
  k_match<<<g2, 256, 0, stream>>>(pk, w64, M, T, V, tPer2);

  size_t smem = (size_t)T * LMAX * sizeof(float);  // 64 KiB
  k_scan<<<2, 256, smem, stream>>>(M, aD, cntA, bD, cntB, aL, bL, T);

  const int tPer5 = 32;
  dim3 g5(V / 256, T / tPer5);
  k_out<<<g5, 256, 0, stream>>>(pk, w64, aL, bL, out, T, V, tPer5);
}

// Round 2
// 72.506 us; speedup vs baseline: 2.6314x; 2.6314x over previous
//
#include <hip/hip_runtime.h>
#include <stdint.h>

#define LMAX 8
#define KCH 32      // chunk length
#define NC  64      // chunks = T/KCH (T=2048)
#define LN2D 0.6931471805599453

struct __align__(16) PK { unsigned long long key; float logp; int len; };

// exact power-of-2 helpers (m must be a positive normal double)
__device__ __forceinline__ int exp2i(double m) {
  return (int)((__double_as_longlong(m) >> 52) & 0x7ff) - 1023;
}
__device__ __forceinline__ double pow2d(int e) {  // 2^e, |e| < 1023
  return __longlong_as_double((long long)(1023 + e) << 52);
}

// K1: pack pieces into 64-bit keys, pack sequence windows, zero M.
__global__ void k_prep(const int* __restrict__ seq, const int* __restrict__ pieces,
                       const int* __restrict__ plens, const float* __restrict__ logp,
                       PK* __restrict__ pk, unsigned long long* __restrict__ w64,
                       float* __restrict__ M, int T, int V) {
  int idx = blockIdx.x * blockDim.x + threadIdx.x;
  if (idx < V) {
    const int* pr = pieces + idx * LMAX;
    int len = plens[idx];
    unsigned long long key = 0ull;
    #pragma unroll
    for (int l = 0; l < LMAX; ++l) {
      unsigned long long b = (unsigned long long)(pr[l] & 0xFF);
      if (l < len) key |= b << (8 * l);
    }
    PK o; o.key = key; o.logp = logp[idx]; o.len = len;
    pk[idx] = o;
  } else if (idx < V + T) {
    int t = idx - V;
    unsigned long long w = 0ull;
    #pragma unroll
    for (int l = 0; l < LMAX; ++l) {
      int pos = t + l;
      unsigned long long b = (pos < T) ? (unsigned long long)(seq[pos] & 0xFF) : 0xFFull;
      w |= b << (8 * l);
    }
    w64[t] = w;
  } else if (idx < V + T + T * LMAX) {
    M[idx - V - T] = 0.f;
  }
}

// K2: M[t][len-1] += p_v for every matching (t,v).
__global__ void k_match(const PK* __restrict__ pk, const unsigned long long* __restrict__ w64,
                        float* __restrict__ M, int T, int V, int tPer) {
  int v = blockIdx.x * blockDim.x + threadIdx.x;
  PK p = pk[v];
  unsigned long long mask = (p.len >= 8) ? ~0ull : ((1ull << (8 * p.len)) - 1ull);
  unsigned long long key = p.key;
  int t0 = blockIdx.y * tPer;
  float prob = -1.f;
  for (int t = t0; t < t0 + tPer; ++t) {
    unsigned long long w = w64[t];
    if (((w ^ key) & mask) == 0ull) {
      if (prob < 0.f) prob = expf(p.logp);
      atomicAdd(&M[t * LMAX + (p.len - 1)], prob);
    }
  }
}

// K3: chunked parallel linear scan (order-8), fp64 with exact pow2 rescaling.
// One block, 256 threads. tid<128: alpha (push-form), else beta (window-form).
__global__ __launch_bounds__(256) void k_scan(const float* __restrict__ M,
        double* __restrict__ aD, double* __restrict__ bD,
        float* __restrict__ aL, float* __restrict__ bL, int T) {
  __shared__ float  Wt[2][64][65];     // [dir][i*8+j][chunk], +1 pad -> conflict-free
  __shared__ double Ust[2][NC][8];     // per-chunk start state
  __shared__ int    EW[2][NC];         // chunk-matrix pow2 exponent
  __shared__ int    Eacc[2][NC];       // accumulated exponent at chunk start
  const int tid = threadIdx.x;
  const float4* Mv = (const float4*)M;

  // ---------------- phase 1: chunk transfer matrices ----------------
  {
    const int dir = tid >> 7;          // 0=alpha, 1=beta
    const int lt  = tid & 127;
    const int c   = lt >> 1, h = lt & 1;   // 2 lanes/chunk, 4 basis cols each
    const int base = c * KCH;
    double st[8][4];
    #pragma unroll
    for (int i = 0; i < 8; ++i)
      #pragma unroll
      for (int bb = 0; bb < 4; ++bb)
        st[i][bb] = (i == 4 * h + bb) ? 1.0 : 0.0;

    if (dir == 0) {  // alpha: s = base..base+K-1, row M[s], push-form
      float4 ra = Mv[base * 2], rb = Mv[base * 2 + 1];
      for (int kg = 0; kg < KCH / 8; ++kg) {
        #pragma unroll
        for (int kk = 0; kk < 8; ++kk) {
          int k = kg * 8 + kk;
          float4 c0 = ra, c1 = rb;
          int nk = (k + 1 < KCH) ? k + 1 : KCH - 1;
          ra = Mv[(base + nk) * 2]; rb = Mv[(base + nk) * 2 + 1];
          double r0=c0.x,r1=c0.y,r2=c0.z,r3=c0.w,r4=c1.x,r5=c1.y,r6=c1.z,r7=c1.w;
          #pragma unroll
          for (int bb = 0; bb < 4; ++bb) {
            double a_ = st[kk & 7][bb];
            st[(kk+1)&7][bb] = fma(a_, r0, st[(kk+1)&7][bb]);
            st[(kk+2)&7][bb] = fma(a_, r1, st[(kk+2)&7][bb]);
            st[(kk+3)&7][bb] = fma(a_, r2, st[(kk+3)&7][bb]);
            st[(kk+4)&7][bb] = fma(a_, r3, st[(kk+4)&7][bb]);
            st[(kk+5)&7][bb] = fma(a_, r4, st[(kk+5)&7][bb]);
            st[(kk+6)&7][bb] = fma(a_, r5, st[(kk+6)&7][bb]);
            st[(kk+7)&7][bb] = fma(a_, r6, st[(kk+7)&7][bb]);
            st[kk & 7][bb]   = a_ * r7;
          }
        }
      }
    } else {  // beta: t = base+K-1 .. base, row M[t], window-form
      float4 ra = Mv[(base + KCH - 1) * 2], rb = Mv[(base + KCH - 1) * 2 + 1];
      for (int kg = 0; kg < KCH / 8; ++kg) {
        #pragma unroll
        for (int kk = 0; kk < 8; ++kk) {
          int k = kg * 8 + kk;
          float4 c0 = ra, c1 = rb;
          int nk = (k + 1 < KCH) ? k + 1 : KCH - 1;
          int nt = base + KCH - 1 - nk;
          ra = Mv[nt * 2]; rb = Mv[nt * 2 + 1];
          double r0=c0.x,r1=c0.y,r2=c0.z,r3=c0.w,r4=c1.x,r5=c1.y,r6=c1.z,r7=c1.w;
          #pragma unroll
          for (int bb = 0; bb < 4; ++bb) {
            double nb =            r0 * st[(8 -kk)&7][bb];
            nb = fma(r1, st[(9 -kk)&7][bb], nb);
            nb = fma(r2, st[(10-kk)&7][bb], nb);
            nb = fma(r3, st[(11-kk)&7][bb], nb);
            nb = fma(r4, st[(12-kk)&7][bb], nb);
            nb = fma(r5, st[(13-kk)&7][bb], nb);
            nb = fma(r6, st[(14-kk)&7][bb], nb);
            nb = fma(r7, st[(15-kk)&7][bb], nb);
            st[(7 - kk) & 7][bb] = nb;
          }
        }
      }
    }
    // normalize by exact power of two, store f32 matrix
    double mx = 0.0;
    #pragma unroll
    for (int i = 0; i < 8; ++i)
      #pragma unroll
      for (int bb = 0; bb < 4; ++bb) mx = fmax(mx, st[i][bb]);
    mx = fmax(mx, __shfl_xor(mx, 1));
    int e = exp2i(mx);
    double sc = pow2d(-e);
    #pragma unroll
    for (int i = 0; i < 8; ++i)
      #pragma unroll
      for (int bb = 0; bb < 4; ++bb)
        Wt[dir][i * 8 + 4 * h + bb][c] = (float)(st[i][bb] * sc);
    if (h == 0) EW[dir][c] = e;
  }
  __syncthreads();

  // ---------------- phase 2: sequential chunk combine (waves 0 & 2) --------
  {
    int wv = tid >> 6;
    if ((wv & 1) == 0) {
      const int dir = wv >> 1;
      const int l = tid & 63;          // i = l>>3 (row), j = l&7 (col)
      double uj = ((l & 7) == 0) ? 1.0 : 0.0;   // u = e0
      int ea = 0;
      int c0 = dir ? (NC - 1) : 0;
      double wcur = (double)Wt[dir][l][c0];
      for (int ci = 0; ci < NC; ++ci) {
        int c = dir ? (NC - 1 - ci) : ci;
        int cn = dir ? (NC - 2 - ci) : (ci + 1);
        if (l < 8) Ust[dir][c][l] = uj;
        if (l == 0) Eacc[dir][c] = ea;
        double wnext = (ci + 1 < NC) ? (double)Wt[dir][l][cn] : 0.0;
        double p = wcur * uj;
        p += __shfl_xor(p, 1);
        p += __shfl_xor(p, 2);
        p += __shfl_xor(p, 4);         // p = v_i for i = l>>3
        uj = __shfl(p, ((l & 7) << 3) | (l >> 3));  // transpose -> lane holds v_{l&7}
        ea += EW[dir][c];
        if (ci & 1) {                  // rescale every 2nd chunk (exact pow2)
          double m = uj;
          m = fmax(m, __shfl_xor(m, 1));
          m = fmax(m, __shfl_xor(m, 2));
          m = fmax(m, __shfl_xor(m, 4));
          int ex = exp2i(m);
          uj *= pow2d(-ex);
          ea += ex;
        }
        wcur = wnext;
      }
    }
  }
  __syncthreads();

  // ---------------- phase 3: replay chunks (waves 0 & 2, 1 lane/chunk) -----
  {
    int wv = tid >> 6;
    int c = tid & 63;
    int base = c * KCH;
    if (wv == 0) {
      double st[8];
      #pragma unroll
      for (int i = 0; i < 8; ++i) st[i] = Ust[0][c][i];
      float4 ra = Mv[base * 2], rb = Mv[base * 2 + 1];
      for (int kg = 0; kg < KCH / 8; ++kg) {
        #pragma unroll
        for (int kk = 0; kk < 8; ++kk) {
          int k = kg * 8 + kk;
          float4 c0 = ra, c1 = rb;
          int nk = (k + 1 < KCH) ? k + 1 : KCH - 1;
          ra = Mv[(base + nk) * 2]; rb = Mv[(base + nk) * 2 + 1];
          double r0=c0.x,r1=c0.y,r2=c0.z,r3=c0.w,r4=c1.x,r5=c1.y,r6=c1.z,r7=c1.w;
          double a_ = st[kk & 7];
          st[(kk+1)&7] = fma(a_, r0, st[(kk+1)&7]);
          st[(kk+2)&7] = fma(a_, r1, st[(kk+2)&7]);
          st[(kk+3)&7] = fma(a_, r2, st[(kk+3)&7]);
          st[(kk+4)&7] = fma(a_, r3, st[(kk+4)&7]);
          st[(kk+5)&7] = fma(a_, r4, st[(kk+5)&7]);
          st[(kk+6)&7] = fma(a_, r5, st[(kk+6)&7]);
          st[(kk+7)&7] = fma(a_, r6, st[(kk+7)&7]);
          st[kk & 7]   = a_ * r7;
          aD[base + k + 1] = st[(kk + 1) & 7];
        }
      }
    } else if (wv == 2) {
      double st[8];
      #pragma unroll
      for (int i = 0; i < 8; ++i) st[i] = Ust[1][c][i];
      float4 ra = Mv[(base + KCH - 1) * 2], rb = Mv[(base + KCH - 1) * 2 + 1];
      for (int kg = 0; kg < KCH / 8; ++kg) {
        #pragma unroll
        for (int kk = 0; kk < 8; ++kk) {
          int k = kg * 8 + kk;
          int t = base + KCH - 1 - k;
          float4 c0 = ra, c1 = rb;
          int nk = (k + 1 < KCH) ? k + 1 : KCH - 1;
          int nt = base + KCH - 1 - nk;
          ra = Mv[nt * 2]; rb = Mv[nt * 2 + 1];
          double r0=c0.x,r1=c0.y,r2=c0.z,r3=c0.w,r4=c1.x,r5=c1.y,r6=c1.z,r7=c1.w;
          double nb =            r0 * st[(8 -kk)&7];
          nb = fma(r1, st[(9 -kk)&7], nb);
          nb = fma(r2, st[(10-kk)&7], nb);
          nb = fma(r3, st[(11-kk)&7], nb);
          nb = fma(r4, st[(12-kk)&7], nb);
          nb = fma(r5, st[(13-kk)&7], nb);
          nb = fma(r6, st[(14-kk)&7], nb);
          nb = fma(r7, st[(15-kk)&7], nb);
          st[(7 - kk) & 7] = nb;
          bD[t] = nb;
        }
      }
    }
  }
  __syncthreads();

  // ---------------- phase 4: logs ----------------
  for (int t = tid; t <= T; t += 256) {
    float av = 0.f, bv = 0.f;
    if (t > 0)  av = (float)(log(aD[t]) + (double)Eacc[0][(t - 1) >> 5] * LN2D);
    if (t < T)  bv = (float)(log(bD[t]) + (double)Eacc[1][t >> 5] * LN2D);
    aL[t] = av; bL[t] = bv;
  }
}

// K4: dense output.
__global__ void k_out(const PK* __restrict__ pk, const unsigned long long* __restrict__ w64,
                      const float* __restrict__ aL, const float* __restrict__ bL,
                      float* __restrict__ out, int T, int V, int tPer) {
  int v = blockIdx.x * blockDim.x + threadIdx.x;
  PK p = pk[v];
  unsigned long long mask = (p.len >= 8) ? ~0ull : ((1ull << (8 * p.len)) - 1ull);
  unsigned long long key = p.key;
  float norm = aL[T];
  float base = p.logp - norm;
  int t0 = blockIdx.y * tPer;
  for (int t = t0; t < t0 + tPer; ++t) {
    unsigned long long w = w64[t];
    float val = 0.f;
    if (((w ^ key) & mask) == 0ull)
      val = __expf(aL[t] + base + bL[t + p.len]);
    out[(size_t)t * V + v] = val;
  }
}

extern "C" void kernel_launch(void* const* d_in, const int* in_sizes, int n_in,
                              void* d_out, int out_size, void* d_ws, size_t ws_size,
                              hipStream_t stream) {
  const int* seq    = (const int*)d_in[0];
  const int* pieces = (const int*)d_in[1];
  const int* plens  = (const int*)d_in[2];
  const float* logp = (const float*)d_in[3];
  float* out = (float*)d_out;
  const int T = in_sizes[0];
  const int V = in_sizes[2];

  char* p = (char*)d_ws;
  PK* pk = (PK*)p;                     p += (size_t)V * sizeof(PK);
  unsigned long long* w64 = (unsigned long long*)p; p += (size_t)T * 8;
  float* M = (float*)p;                p += (size_t)T * LMAX * 4;
  double* aD = (double*)p;             p += (size_t)(T + 1) * 8;
  double* bD = (double*)p;             p += (size_t)(T + 1) * 8;
  float* aL = (float*)p;               p += (size_t)(T + 1) * 4;
  float* bL = (float*)p;               p += (size_t)(T + 1) * 4;

  int prepN = V + T + T * LMAX;
  k_prep<<<(prepN + 255) / 256, 256, 0, stream>>>(seq, pieces, plens, logp, pk, w64, M, T, V);

  const int tPer2 = 128;
  dim3 g2(V / 256, T / tPer2);
  k_match<<<g2, 256, 0, stream>>>(pk, w64, M, T, V, tPer2);

  k_scan<<<1, 256, 0, stream>>>(M, aD, bD, aL, bL, T);

  const int tPer5 = 32;
  dim3 g5(V / 256, T / tPer5);
  k_out<<<g5, 256, 0, stream>>>(pk, w64, aL, bL, out, T, V, tPer5);
}

// Round 3
// 60.742 us; speedup vs baseline: 3.1410x; 1.1937x over previous
//
#include <hip/hip_runtime.h>
#include <stdint.h>

#define LMAX 8
#define KCH 32
#define NC  64
#define TT  2048
#define LN2D 0.6931471805599453
#define NEGE (-(1<<28))

struct __align__(16) PK { unsigned long long key; float logp; int len; };

__device__ __forceinline__ int fexp(float m) { return ((__float_as_int(m) >> 23) & 0xFF) - 127; }
__device__ __forceinline__ int fexpbits(float m) { return (__float_as_int(m) >> 23) & 0xFF; }
__device__ __forceinline__ float p2(int e) { return __int_as_float((e + 127) << 23); }      // e in [-126,127]
__device__ __forceinline__ float p2c(int e) { return (e < -126) ? 0.f : p2(e); }            // e <= ~66

// K1: pack pieces into 64-bit keys, pack sequence windows, zero M.
__global__ void k_prep(const int* __restrict__ seq, const int* __restrict__ pieces,
                       const int* __restrict__ plens, const float* __restrict__ logp,
                       PK* __restrict__ pk, unsigned long long* __restrict__ w64,
                       float* __restrict__ M, int T, int V) {
  int idx = blockIdx.x * blockDim.x + threadIdx.x;
  if (idx < V) {
    const int* pr = pieces + idx * LMAX;
    int len = plens[idx];
    unsigned long long key = 0ull;
    #pragma unroll
    for (int l = 0; l < LMAX; ++l) {
      unsigned long long b = (unsigned long long)(pr[l] & 0xFF);
      if (l < len) key |= b << (8 * l);
    }
    PK o; o.key = key; o.logp = logp[idx]; o.len = len;
    pk[idx] = o;
  } else if (idx < V + T) {
    int t = idx - V;
    unsigned long long w = 0ull;
    #pragma unroll
    for (int l = 0; l < LMAX; ++l) {
      int pos = t + l;
      unsigned long long b = (pos < T) ? (unsigned long long)(seq[pos] & 0xFF) : 0xFFull;
      w |= b << (8 * l);
    }
    w64[t] = w;
  } else if (idx < V + T + T * LMAX) {
    M[idx - V - T] = 0.f;
  }
}

// K2: M[t][len-1] += p_v for every matching (t,v).
__global__ void k_match(const PK* __restrict__ pk, const unsigned long long* __restrict__ w64,
                        float* __restrict__ M, int T, int V, int tPer) {
  int v = blockIdx.x * blockDim.x + threadIdx.x;
  PK p = pk[v];
  unsigned long long mask = (p.len >= 8) ? ~0ull : ((1ull << (8 * p.len)) - 1ull);
  unsigned long long key = p.key;
  int t0 = blockIdx.y * tPer;
  float prob = -1.f;
  for (int t = t0; t < t0 + tPer; ++t) {
    unsigned long long w = w64[t];
    if (((w ^ key) & mask) == 0ull) {
      if (prob < 0.f) prob = expf(p.logp);
      atomicAdd(&M[t * LMAX + (p.len - 1)], prob);
    }
  }
}

// K3: three-level chunked linear scan (order-8). f32 combine with exact pow2
// exponent bookkeeping (+2^64 bias vs f32 underflow); fp64 replay.
__global__ __launch_bounds__(512) void k_scan(const float* __restrict__ M,
        float* __restrict__ Wt, float* __restrict__ P,
        double* __restrict__ aD, double* __restrict__ bD,
        float* __restrict__ aL, float* __restrict__ bL) {
  __shared__ float  Gm[2 * 8 * 69];    // group matrices, col-major cols of 8
  __shared__ float  Cs[2 * 64 * 9];    // chunk-start vectors (normalized)
  __shared__ float  Sg[2 * 8 * 9];     // group-start vectors
  __shared__ int    EWc[2 * 64 * 8];   // per-column chunk-matrix exponents
  __shared__ int    EPs[2 * 64 * 8];   // per-(chunk,basis) prefix exponents
  __shared__ int    EGs[2 * 8 * 8];    // per-(group,basis) exponents
  __shared__ int    EaccP[2 * 64];     // chunk-start exponent, PHYSICAL index
  __shared__ int    EsB[2 * 8];        // group-start exponents
  const int tid = threadIdx.x;
  const float4* Mv = (const float4*)M;

  // ---------------- phase 1: chunk transfer matrices (f32, biased) ---------
  {
    const int dir = tid >> 8, lt = tid & 255;
    const int c = lt >> 2, h = lt & 3;          // 4 lanes/chunk, 2 basis cols
    const int base = c * KCH;
    float st[2][8];
    #pragma unroll
    for (int bb = 0; bb < 2; ++bb)
      #pragma unroll
      for (int i = 0; i < 8; ++i) st[bb][i] = (i == 2 * h + bb) ? p2(64) : 0.f;
    int ec = -64;
    if (dir == 0) {
      float4 ra = Mv[base * 2], rb = Mv[base * 2 + 1];
      for (int kg = 0; kg < 4; ++kg) {
        #pragma unroll
        for (int kk = 0; kk < 8; ++kk) {
          int k = kg * 8 + kk;
          float4 c0 = ra, c1 = rb;
          int nk = (k + 1 < KCH) ? k + 1 : KCH - 1;
          ra = Mv[(base + nk) * 2]; rb = Mv[(base + nk) * 2 + 1];
          #pragma unroll
          for (int bb = 0; bb < 2; ++bb) {
            float a_ = st[bb][kk & 7];
            st[bb][(kk + 1) & 7] = fmaf(a_, c0.x, st[bb][(kk + 1) & 7]);
            st[bb][(kk + 2) & 7] = fmaf(a_, c0.y, st[bb][(kk + 2) & 7]);
            st[bb][(kk + 3) & 7] = fmaf(a_, c0.z, st[bb][(kk + 3) & 7]);
            st[bb][(kk + 4) & 7] = fmaf(a_, c0.w, st[bb][(kk + 4) & 7]);
            st[bb][(kk + 5) & 7] = fmaf(a_, c1.x, st[bb][(kk + 5) & 7]);
            st[bb][(kk + 6) & 7] = fmaf(a_, c1.y, st[bb][(kk + 6) & 7]);
            st[bb][(kk + 7) & 7] = fmaf(a_, c1.z, st[bb][(kk + 7) & 7]);
            st[bb][kk & 7]       = a_ * c1.w;
          }
          if (kk == 3 || kk == 7) {
            float mx = 0.f;
            #pragma unroll
            for (int bb = 0; bb < 2; ++bb)
              #pragma unroll
              for (int i = 0; i < 8; ++i) mx = fmaxf(mx, st[bb][i]);
            if (fexpbits(mx) != 0) {
              int e = fexp(mx), d = 64 - e;
              float m1 = p2(d / 2), m2 = p2(d - d / 2);
              #pragma unroll
              for (int bb = 0; bb < 2; ++bb)
                #pragma unroll
                for (int i = 0; i < 8; ++i) st[bb][i] = st[bb][i] * m1 * m2;
              ec += e - 64;
            }
          }
        }
      }
    } else {
      float4 ra = Mv[(base + KCH - 1) * 2], rb = Mv[(base + KCH - 1) * 2 + 1];
      for (int kg = 0; kg < 4; ++kg) {
        #pragma unroll
        for (int kk = 0; kk < 8; ++kk) {
          int k = kg * 8 + kk;
          float4 c0 = ra, c1 = rb;
          int nk = (k + 1 < KCH) ? k + 1 : KCH - 1;
          int nt = base + KCH - 1 - nk;
          ra = Mv[nt * 2]; rb = Mv[nt * 2 + 1];
          #pragma unroll
          for (int bb = 0; bb < 2; ++bb) {
            float nb =      c0.x * st[bb][(8  - kk) & 7];
            nb = fmaf(c0.y, st[bb][(9  - kk) & 7], nb);
            nb = fmaf(c0.z, st[bb][(10 - kk) & 7], nb);
            nb = fmaf(c0.w, st[bb][(11 - kk) & 7], nb);
            nb = fmaf(c1.x, st[bb][(12 - kk) & 7], nb);
            nb = fmaf(c1.y, st[bb][(13 - kk) & 7], nb);
            nb = fmaf(c1.z, st[bb][(14 - kk) & 7], nb);
            nb = fmaf(c1.w, st[bb][(15 - kk) & 7], nb);
            st[bb][(7 - kk) & 7] = nb;
          }
          if (kk == 3 || kk == 7) {
            float mx = 0.f;
            #pragma unroll
            for (int bb = 0; bb < 2; ++bb)
              #pragma unroll
              for (int i = 0; i < 8; ++i) mx = fmaxf(mx, st[bb][i]);
            if (fexpbits(mx) != 0) {
              int e = fexp(mx), d = 64 - e;
              float m1 = p2(d / 2), m2 = p2(d - d / 2);
              #pragma unroll
              for (int bb = 0; bb < 2; ++bb)
                #pragma unroll
                for (int i = 0; i < 8; ++i) st[bb][i] = st[bb][i] * m1 * m2;
              ec += e - 64;
            }
          }
        }
      }
    }
    // normalize pair to max in [1,2), store columns (col-major), exponents
    float mx = 0.f;
    #pragma unroll
    for (int bb = 0; bb < 2; ++bb)
      #pragma unroll
      for (int i = 0; i < 8; ++i) mx = fmaxf(mx, st[bb][i]);
    int lc = dir ? (NC - 1 - c) : c;
    float* wp = Wt + (dir * 64 + lc) * 68;
    int ew;
    if (fexpbits(mx) == 0) {
      ew = NEGE;
      #pragma unroll
      for (int bb = 0; bb < 2; ++bb)
        #pragma unroll
        for (int i = 0; i < 8; ++i) wp[(2 * h + bb) * 8 + i] = 0.f;
    } else {
      int e = fexp(mx);
      float sc = p2(-e);
      ew = ec + e;
      #pragma unroll
      for (int bb = 0; bb < 2; ++bb)
        #pragma unroll
        for (int i = 0; i < 8; ++i) wp[(2 * h + bb) * 8 + i] = st[bb][i] * sc;
    }
    EWc[(dir * 64 + lc) * 8 + 2 * h]     = ew;
    EWc[(dir * 64 + lc) * 8 + 2 * h + 1] = ew;
  }
  __syncthreads();

  // ---------------- level A: basis through each group (16 tasks x 8 lanes) -
  if (tid < 128) {
    const int dir = tid >> 6, w = (tid >> 3) & 7, b = tid & 7;
    float v[8];
    #pragma unroll
    for (int i = 0; i < 8; ++i) v[i] = (i == b) ? 1.f : 0.f;
    int ec = 0;
    for (int c = 0; c < 8; ++c) {
      int lc = w * 8 + c;
      float* pp = P + (dir * 64 + lc) * 69 + b * 8;
      #pragma unroll
      for (int i = 0; i < 8; ++i) pp[i] = v[i];
      EPs[(dir * 64 + lc) * 8 + b] = ec;
      const float* wp = Wt + (dir * 64 + lc) * 68;
      int ew[8];
      #pragma unroll
      for (int j = 0; j < 8; ++j) ew[j] = EWc[(dir * 64 + lc) * 8 + j];
      int emax = ew[0];
      #pragma unroll
      for (int j = 1; j < 8; ++j) emax = max(emax, ew[j]);
      float nv[8] = {0, 0, 0, 0, 0, 0, 0, 0};
      #pragma unroll
      for (int j = 0; j < 8; ++j) {
        float tj = v[j] * p2c(ew[j] - emax + 64);
        float4 ca = *(const float4*)(wp + j * 8);
        float4 cb = *(const float4*)(wp + j * 8 + 4);
        nv[0] = fmaf(tj, ca.x, nv[0]); nv[1] = fmaf(tj, ca.y, nv[1]);
        nv[2] = fmaf(tj, ca.z, nv[2]); nv[3] = fmaf(tj, ca.w, nv[3]);
        nv[4] = fmaf(tj, cb.x, nv[4]); nv[5] = fmaf(tj, cb.y, nv[5]);
        nv[6] = fmaf(tj, cb.z, nv[6]); nv[7] = fmaf(tj, cb.w, nv[7]);
      }
      float mx = 0.f;
      #pragma unroll
      for (int i = 0; i < 8; ++i) mx = fmaxf(mx, nv[i]);
      if (fexpbits(mx) == 0) {
        #pragma unroll
        for (int i = 0; i < 8; ++i) v[i] = 0.f;
        ec = NEGE;
      } else {
        int e = fexp(mx);
        float sc = p2(-e);
        #pragma unroll
        for (int i = 0; i < 8; ++i) v[i] = nv[i] * sc;
        ec = ec + emax + e - 64;
      }
    }
    float* gp = Gm + (dir * 8 + w) * 69 + b * 8;
    #pragma unroll
    for (int i = 0; i < 8; ++i) gp[i] = v[i];
    EGs[(dir * 8 + w) * 8 + b] = ec;
  }
  __syncthreads();

  // ---------------- level B: sequential over 8 groups (8 lanes per dir) ----
  if (tid < 8 || (tid >= 64 && tid < 72)) {
    const int dir = (tid >= 64) ? 1 : 0, j = tid & 7;
    float s[8];
    #pragma unroll
    for (int i = 0; i < 8; ++i) s[i] = (i == 0) ? 1.f : 0.f;
    int Es = 0;
    for (int w = 0; w < 8; ++w) {
      float sj = s[0];
      #pragma unroll
      for (int i = 1; i < 8; ++i) if (j == i) sj = s[i];
      Sg[(dir * 8 + w) * 9 + j] = sj;
      if (j == 0) EsB[dir * 8 + w] = Es;
      int eg[8];
      #pragma unroll
      for (int i = 0; i < 8; ++i) eg[i] = EGs[(dir * 8 + w) * 8 + i];
      int egmax = eg[0];
      #pragma unroll
      for (int i = 1; i < 8; ++i) egmax = max(egmax, eg[i]);
      int egj = eg[0];
      #pragma unroll
      for (int i = 1; i < 8; ++i) if (j == i) egj = eg[i];
      float tb = sj * p2c(egj - egmax + 64);
      const float* gp = Gm + (dir * 8 + w) * 69 + j * 8;
      float p[8];
      #pragma unroll
      for (int i = 0; i < 8; ++i) p[i] = gp[i] * tb;
      #pragma unroll
      for (int m = 1; m <= 4; m <<= 1)
        #pragma unroll
        for (int i = 0; i < 8; ++i) p[i] += __shfl_xor(p[i], m);
      float mx = 0.f;
      #pragma unroll
      for (int i = 0; i < 8; ++i) mx = fmaxf(mx, p[i]);
      int e = fexp(mx);
      float sc = p2(-e);
      #pragma unroll
      for (int i = 0; i < 8; ++i) s[i] = p[i] * sc;
      Es += egmax + e - 64;
    }
  }
  __syncthreads();

  // ---------------- level C: chunk-start vectors (parallel) ----------------
  if (tid < 128) {
    const int dir = tid >> 6, lc = tid & 63, w = lc >> 3;
    float sg[8];
    #pragma unroll
    for (int b = 0; b < 8; ++b) sg[b] = Sg[(dir * 8 + w) * 9 + b];
    int Es = EsB[dir * 8 + w];
    int ep[8];
    #pragma unroll
    for (int b = 0; b < 8; ++b) ep[b] = EPs[(dir * 64 + lc) * 8 + b];
    int epmax = ep[0];
    #pragma unroll
    for (int b = 1; b < 8; ++b) epmax = max(epmax, ep[b]);
    float cs[8] = {0, 0, 0, 0, 0, 0, 0, 0};
    #pragma unroll
    for (int b = 0; b < 8; ++b) {
      float coef = sg[b] * p2c(ep[b] - epmax + 64);
      const float* pp = P + (dir * 64 + lc) * 69 + b * 8;
      #pragma unroll
      for (int i = 0; i < 8; ++i) cs[i] = fmaf(coef, pp[i], cs[i]);
    }
    float mx = 0.f;
    #pragma unroll
    for (int i = 0; i < 8; ++i) mx = fmaxf(mx, cs[i]);
    float* cp = Cs + (dir * 64 + lc) * 9;
    int phys = dir ? (63 - lc) : lc;
    if (fexpbits(mx) == 0) {
      #pragma unroll
      for (int i = 0; i < 8; ++i) cp[i] = 0.f;
      EaccP[dir * 64 + phys] = NEGE;
    } else {
      int e = fexp(mx);
      float sc = p2(-e);
      #pragma unroll
      for (int i = 0; i < 8; ++i) cp[i] = cs[i] * sc;
      EaccP[dir * 64 + phys] = Es + epmax + e - 64;
    }
  }
  __syncthreads();

  // ---------------- replay chunks (fp64), 1 lane/chunk ---------------------
  if (tid < 64) {            // alpha, physical chunk = tid
    int c = tid, base = c * KCH;
    const float* cp = Cs + c * 9;
    double st[8];
    #pragma unroll
    for (int i = 0; i < 8; ++i) st[i] = (double)cp[i];
    float4 ra = Mv[base * 2], rb = Mv[base * 2 + 1];
    for (int kg = 0; kg < KCH / 8; ++kg) {
      #pragma unroll
      for (int kk = 0; kk < 8; ++kk) {
        int k = kg * 8 + kk;
        float4 c0 = ra, c1 = rb;
        int nk = (k + 1 < KCH) ? k + 1 : KCH - 1;
        ra = Mv[(base + nk) * 2]; rb = Mv[(base + nk) * 2 + 1];
        double r0 = c0.x, r1 = c0.y, r2 = c0.z, r3 = c0.w;
        double r4 = c1.x, r5 = c1.y, r6 = c1.z, r7 = c1.w;
        double a_ = st[kk & 7];
        st[(kk + 1) & 7] = fma(a_, r0, st[(kk + 1) & 7]);
        st[(kk + 2) & 7] = fma(a_, r1, st[(kk + 2) & 7]);
        st[(kk + 3) & 7] = fma(a_, r2, st[(kk + 3) & 7]);
        st[(kk + 4) & 7] = fma(a_, r3, st[(kk + 4) & 7]);
        st[(kk + 5) & 7] = fma(a_, r4, st[(kk + 5) & 7]);
        st[(kk + 6) & 7] = fma(a_, r5, st[(kk + 6) & 7]);
        st[(kk + 7) & 7] = fma(a_, r6, st[(kk + 7) & 7]);
        st[kk & 7]       = a_ * r7;
        aD[base + k + 1] = st[(kk + 1) & 7];
      }
    }
  } else if (tid < 128) {    // beta, physical chunk = tid-64
    int c = tid - 64, base = c * KCH;
    const float* cp = Cs + (64 + 63 - c) * 9;
    double st[8];
    #pragma unroll
    for (int i = 0; i < 8; ++i) st[i] = (double)cp[i];
    float4 ra = Mv[(base + KCH - 1) * 2], rb = Mv[(base + KCH - 1) * 2 + 1];
    for (int kg = 0; kg < KCH / 8; ++kg) {
      #pragma unroll
      for (int kk = 0; kk < 8; ++kk) {
        int k = kg * 8 + kk;
        int t = base + KCH - 1 - k;
        float4 c0 = ra, c1 = rb;
        int nk = (k + 1 < KCH) ? k + 1 : KCH - 1;
        int nt = base + KCH - 1 - nk;
        ra = Mv[nt * 2]; rb = Mv[nt * 2 + 1];
        double r0 = c0.x, r1 = c0.y, r2 = c0.z, r3 = c0.w;
        double r4 = c1.x, r5 = c1.y, r6 = c1.z, r7 = c1.w;
        double nb =  r0 * st[(8  - kk) & 7];
        nb = fma(r1, st[(9  - kk) & 7], nb);
        nb = fma(r2, st[(10 - kk) & 7], nb);
        nb = fma(r3, st[(11 - kk) & 7], nb);
        nb = fma(r4, st[(12 - kk) & 7], nb);
        nb = fma(r5, st[(13 - kk) & 7], nb);
        nb = fma(r6, st[(14 - kk) & 7], nb);
        nb = fma(r7, st[(15 - kk) & 7], nb);
        st[(7 - kk) & 7] = nb;
        bD[t] = nb;
      }
    }
  }
  __syncthreads();

  // ---------------- phase 4: logs (mantissa split + log2f) -----------------
  for (int t = tid; t <= TT; t += 512) {
    float av = 0.f, bv = 0.f;
    if (t > 0) {
      long long bits = __double_as_longlong(aD[t]);
      int e2 = (int)((bits >> 52) & 0x7ff) - 1023;
      double mant = __longlong_as_double((bits & 0xFFFFFFFFFFFFFLL) | 0x3FF0000000000000LL);
      float lg = log2f((float)mant);
      av = (float)(((double)(e2 + EaccP[(t - 1) >> 5]) + (double)lg) * LN2D);
    }
    if (t < TT) {
      long long bits = __double_as_longlong(bD[t]);
      int e2 = (int)((bits >> 52) & 0x7ff) - 1023;
      double mant = __longlong_as_double((bits & 0xFFFFFFFFFFFFFLL) | 0x3FF0000000000000LL);
      float lg = log2f((float)mant);
      bv = (float)(((double)(e2 + EaccP[64 + (t >> 5)]) + (double)lg) * LN2D);
    }
    aL[t] = av; bL[t] = bv;
  }
}

// K4: dense output.
__global__ void k_out(const PK* __restrict__ pk, const unsigned long long* __restrict__ w64,
                      const float* __restrict__ aL, const float* __restrict__ bL,
                      float* __restrict__ out, int T, int V, int tPer) {
  int v = blockIdx.x * blockDim.x + threadIdx.x;
  PK p = pk[v];
  unsigned long long mask = (p.len >= 8) ? ~0ull : ((1ull << (8 * p.len)) - 1ull);
  unsigned long long key = p.key;
  float norm = aL[T];
  float base = p.logp - norm;
  int t0 = blockIdx.y * tPer;
  for (int t = t0; t < t0 + tPer; ++t) {
    unsigned long long w = w64[t];
    float val = 0.f;
    if (((w ^ key) & mask) == 0ull)
      val = __expf(aL[t] + base + bL[t + p.len]);
    out[(size_t)t * V + v] = val;
  }
}

extern "C" void kernel_launch(void* const* d_in, const int* in_sizes, int n_in,
                              void* d_out, int out_size, void* d_ws, size_t ws_size,
                              hipStream_t stream) {
  const int* seq    = (const int*)d_in[0];
  const int* pieces = (const int*)d_in[1];
  const int* plens  = (const int*)d_in[2];
  const float* logp = (const float*)d_in[3];
  float* out = (float*)d_out;
  const int T = in_sizes[0];
  const int V = in_sizes[2];

  char* p = (char*)d_ws;
  PK* pk = (PK*)p;                                   p += (size_t)V * sizeof(PK);
  unsigned long long* w64 = (unsigned long long*)p;  p += (size_t)T * 8;
  float* M = (float*)p;                              p += (size_t)T * LMAX * 4;
  double* aD = (double*)p;                           p += 16400;
  double* bD = (double*)p;                           p += 16400;
  float* aL = (float*)p;                             p += 8208;
  float* bL = (float*)p;                             p += 8208;
  float* Wt = (float*)p;                             p += (size_t)2 * 64 * 68 * 4;
  float* Pm = (float*)p;                             p += (size_t)2 * 64 * 69 * 4;

  int prepN = V + T + T * LMAX;
  k_prep<<<(prepN + 255) / 256, 256, 0, stream>>>(seq, pieces, plens, logp, pk, w64, M, T, V);

  const int tPer2 = 128;
  dim3 g2(V / 256, T / tPer2);
  k_match<<<g2, 256, 0, stream>>>(pk, w64, M, T, V, tPer2);

  k_scan<<<1, 512, 0, stream>>>(M, Wt, Pm, aD, bD, aL, bL);

  const int tPer5 = 32;
  dim3 g5(V / 256, T / tPer5);
  k_out<<<g5, 256, 0, stream>>>(pk, w64, aL, bL, out, T, V, tPer5);
}

// Round 4
// 59.391 us; speedup vs baseline: 3.2124x; 1.0227x over previous
//
#include <hip/hip_runtime.h>
#include <stdint.h>

#define LMAX 8
#define KCH 32
#define NC  64
#define TT  2048
#define LN2D 0.6931471805599453
#define NEGE (-(1<<28))

struct __align__(16) PK { unsigned long long key; float logp; int len; };

__device__ __forceinline__ int fexp(float m) { return ((__float_as_int(m) >> 23) & 0xFF) - 127; }
__device__ __forceinline__ int fexpbits(float m) { return (__float_as_int(m) >> 23) & 0xFF; }
__device__ __forceinline__ float p2(int e) { return __int_as_float((e + 127) << 23); }
__device__ __forceinline__ float p2c(int e) { return (e < -126) ? 0.f : p2(e); }

// K1: pack pieces into 64-bit keys, pack sequence windows, zero M.
__global__ void k_prep(const int* __restrict__ seq, const int* __restrict__ pieces,
                       const int* __restrict__ plens, const float* __restrict__ logp,
                       PK* __restrict__ pk, unsigned long long* __restrict__ w64,
                       float* __restrict__ M, int T, int V) {
  int idx = blockIdx.x * blockDim.x + threadIdx.x;
  if (idx < V) {
    const int* pr = pieces + idx * LMAX;
    int len = plens[idx];
    unsigned long long key = 0ull;
    #pragma unroll
    for (int l = 0; l < LMAX; ++l) {
      unsigned long long b = (unsigned long long)(pr[l] & 0xFF);
      if (l < len) key |= b << (8 * l);
    }
    PK o; o.key = key; o.logp = logp[idx]; o.len = len;
    pk[idx] = o;
  } else if (idx < V + T) {
    int t = idx - V;
    unsigned long long w = 0ull;
    #pragma unroll
    for (int l = 0; l < LMAX; ++l) {
      int pos = t + l;
      unsigned long long b = (pos < T) ? (unsigned long long)(seq[pos] & 0xFF) : 0xFFull;
      w |= b << (8 * l);
    }
    w64[t] = w;
  } else if (idx < V + T + T * LMAX) {
    M[idx - V - T] = 0.f;
  }
}

// K2: M[t][len-1] += p_v for every matching (t,v).
__global__ void k_match(const PK* __restrict__ pk, const unsigned long long* __restrict__ w64,
                        float* __restrict__ M, int T, int V, int tPer) {
  int v = blockIdx.x * blockDim.x + threadIdx.x;
  PK p = pk[v];
  unsigned long long mask = (p.len >= 8) ? ~0ull : ((1ull << (8 * p.len)) - 1ull);
  unsigned long long key = p.key;
  int t0 = blockIdx.y * tPer;
  float prob = -1.f;
  for (int t = t0; t < t0 + tPer; ++t) {
    unsigned long long w = w64[t];
    if (((w ^ key) & mask) == 0ull) {
      if (prob < 0.f) prob = expf(p.logp);
      atomicAdd(&M[t * LMAX + (p.len - 1)], prob);
    }
  }
}

// K3a: per-(dir,chunk,basis-col) chunk transfer-matrix columns. 128 tasks x 8
// lanes, fully independent (per-column pow2 exponents, no cross-lane ops).
__global__ __launch_bounds__(512) void k_chunks(const float* __restrict__ M,
        float* __restrict__ Wt, int* __restrict__ EWc) {
  int gtid = blockIdx.x * 512 + threadIdx.x;   // 0..1023
  int task = gtid >> 3, b = gtid & 7;
  int dir = task >> 6, c = task & 63;
  int base = c * KCH;
  const float4* Mv = (const float4*)M;
  float v[8];
  #pragma unroll
  for (int i = 0; i < 8; ++i) v[i] = (i == b) ? 1.f : 0.f;
  int ec = 0;
  if (dir == 0) {          // alpha push-form
    float4 ra = Mv[base * 2], rb = Mv[base * 2 + 1];
    for (int kg = 0; kg < 4; ++kg) {
      #pragma unroll
      for (int kk = 0; kk < 8; ++kk) {
        int k = kg * 8 + kk;
        float4 c0 = ra, c1 = rb;
        int nk = (k + 1 < KCH) ? k + 1 : KCH - 1;
        ra = Mv[(base + nk) * 2]; rb = Mv[(base + nk) * 2 + 1];
        float a_ = v[kk & 7];
        v[(kk + 1) & 7] = fmaf(a_, c0.x, v[(kk + 1) & 7]);
        v[(kk + 2) & 7] = fmaf(a_, c0.y, v[(kk + 2) & 7]);
        v[(kk + 3) & 7] = fmaf(a_, c0.z, v[(kk + 3) & 7]);
        v[(kk + 4) & 7] = fmaf(a_, c0.w, v[(kk + 4) & 7]);
        v[(kk + 5) & 7] = fmaf(a_, c1.x, v[(kk + 5) & 7]);
        v[(kk + 6) & 7] = fmaf(a_, c1.y, v[(kk + 6) & 7]);
        v[(kk + 7) & 7] = fmaf(a_, c1.z, v[(kk + 7) & 7]);
        v[kk & 7]       = a_ * c1.w;
        if (kk == 3 || kk == 7) {
          float mx = 0.f;
          #pragma unroll
          for (int i = 0; i < 8; ++i) mx = fmaxf(mx, v[i]);
          if (fexpbits(mx) != 0) {
            int e = fexp(mx); float sc = p2(-e);
            #pragma unroll
            for (int i = 0; i < 8; ++i) v[i] *= sc;
            ec += e;
          }
        }
      }
    }
  } else {                 // beta window-form
    float4 ra = Mv[(base + KCH - 1) * 2], rb = Mv[(base + KCH - 1) * 2 + 1];
    for (int kg = 0; kg < 4; ++kg) {
      #pragma unroll
      for (int kk = 0; kk < 8; ++kk) {
        int k = kg * 8 + kk;
        float4 c0 = ra, c1 = rb;
        int nk = (k + 1 < KCH) ? k + 1 : KCH - 1;
        int nt = base + KCH - 1 - nk;
        ra = Mv[nt * 2]; rb = Mv[nt * 2 + 1];
        float nb =      c0.x * v[(8  - kk) & 7];
        nb = fmaf(c0.y, v[(9  - kk) & 7], nb);
        nb = fmaf(c0.z, v[(10 - kk) & 7], nb);
        nb = fmaf(c0.w, v[(11 - kk) & 7], nb);
        nb = fmaf(c1.x, v[(12 - kk) & 7], nb);
        nb = fmaf(c1.y, v[(13 - kk) & 7], nb);
        nb = fmaf(c1.z, v[(14 - kk) & 7], nb);
        nb = fmaf(c1.w, v[(15 - kk) & 7], nb);
        v[(7 - kk) & 7] = nb;
        if (kk == 3 || kk == 7) {
          float mx = 0.f;
          #pragma unroll
          for (int i = 0; i < 8; ++i) mx = fmaxf(mx, v[i]);
          if (fexpbits(mx) != 0) {
            int e = fexp(mx); float sc = p2(-e);
            #pragma unroll
            for (int i = 0; i < 8; ++i) v[i] *= sc;
            ec += e;
          }
        }
      }
    }
  }
  float mx = 0.f;
  #pragma unroll
  for (int i = 0; i < 8; ++i) mx = fmaxf(mx, v[i]);
  int ltask = dir * 64 + (dir ? 63 - c : c);   // logical order for combine
  float* wp = Wt + ltask * 64;
  if (fexpbits(mx) == 0) {
    #pragma unroll
    for (int i = 0; i < 8; ++i) wp[b * 8 + i] = 0.f;
    EWc[ltask * 8 + b] = NEGE;
  } else {
    int e = fexp(mx); float sc = p2(-e);
    #pragma unroll
    for (int i = 0; i < 8; ++i) wp[b * 8 + i] = v[i] * sc;
    EWc[ltask * 8 + b] = ec + e;
  }
}

// K3b: hierarchical combine (levels A/B/C), single block, LDS-resident Wt.
__global__ __launch_bounds__(256) void k_combine(const float* __restrict__ Wt,
        const int* __restrict__ EWc, float* __restrict__ Pm,
        float* __restrict__ Cs, int* __restrict__ Eacc) {
  __shared__ float sWt[128][68];
  __shared__ int   sEW[128 * 8];
  __shared__ int   sEP[128 * 8];
  __shared__ float Gm[16 * 69];
  __shared__ float Sg[16 * 9];
  __shared__ int   EGs[16 * 8];
  __shared__ int   EsB[16];
  const int tid = threadIdx.x;

  for (int i = tid; i < 128 * 16; i += 256) {
    int task = i >> 4, q = i & 15;
    float4 v4 = ((const float4*)Wt)[i];
    *(float4*)&sWt[task][q * 4] = v4;
  }
  for (int i = tid; i < 1024; i += 256) sEW[i] = EWc[i];
  __syncthreads();

  // level A: basis through each group of 8 chunks (16 tasks x 8 basis lanes)
  if (tid < 128) {
    const int dir = tid >> 6, w = (tid >> 3) & 7, b = tid & 7;
    float v[8];
    #pragma unroll
    for (int i = 0; i < 8; ++i) v[i] = (i == b) ? 1.f : 0.f;
    int ec = 0;
    for (int c = 0; c < 8; ++c) {
      int lc = w * 8 + c, lt = dir * 64 + lc;
      float* pp = Pm + lt * 64 + b * 8;
      #pragma unroll
      for (int i = 0; i < 8; ++i) pp[i] = v[i];
      sEP[lt * 8 + b] = ec;
      const float* wp = &sWt[lt][0];
      int ew[8];
      #pragma unroll
      for (int j = 0; j < 8; ++j) ew[j] = sEW[lt * 8 + j];
      int emax = ew[0];
      #pragma unroll
      for (int j = 1; j < 8; ++j) emax = max(emax, ew[j]);
      float nv[8] = {0, 0, 0, 0, 0, 0, 0, 0};
      #pragma unroll
      for (int j = 0; j < 8; ++j) {
        float tj = v[j] * p2c(ew[j] - emax + 64);
        float4 ca = *(const float4*)(wp + j * 8);
        float4 cb = *(const float4*)(wp + j * 8 + 4);
        nv[0] = fmaf(tj, ca.x, nv[0]); nv[1] = fmaf(tj, ca.y, nv[1]);
        nv[2] = fmaf(tj, ca.z, nv[2]); nv[3] = fmaf(tj, ca.w, nv[3]);
        nv[4] = fmaf(tj, cb.x, nv[4]); nv[5] = fmaf(tj, cb.y, nv[5]);
        nv[6] = fmaf(tj, cb.z, nv[6]); nv[7] = fmaf(tj, cb.w, nv[7]);
      }
      float mx = 0.f;
      #pragma unroll
      for (int i = 0; i < 8; ++i) mx = fmaxf(mx, nv[i]);
      if (fexpbits(mx) == 0) {
        #pragma unroll
        for (int i = 0; i < 8; ++i) v[i] = 0.f;
        ec = NEGE;
      } else {
        int e = fexp(mx); float sc = p2(-e);
        #pragma unroll
        for (int i = 0; i < 8; ++i) v[i] = nv[i] * sc;
        ec = ec + emax + e - 64;
      }
    }
    float* gp = Gm + (dir * 8 + w) * 69 + b * 8;
    #pragma unroll
    for (int i = 0; i < 8; ++i) gp[i] = v[i];
    EGs[(dir * 8 + w) * 8 + b] = ec;
  }
  __syncthreads();

  // level B: sequential over 8 groups (8 lanes per dir)
  if (tid < 8 || (tid >= 64 && tid < 72)) {
    const int dir = (tid >= 64) ? 1 : 0, j = tid & 7;
    float s[8];
    #pragma unroll
    for (int i = 0; i < 8; ++i) s[i] = (i == 0) ? 1.f : 0.f;
    int Es = 0;
    for (int w = 0; w < 8; ++w) {
      float sj = s[0];
      #pragma unroll
      for (int i = 1; i < 8; ++i) if (j == i) sj = s[i];
      Sg[(dir * 8 + w) * 9 + j] = sj;
      if (j == 0) EsB[dir * 8 + w] = Es;
      int eg[8];
      #pragma unroll
      for (int i = 0; i < 8; ++i) eg[i] = EGs[(dir * 8 + w) * 8 + i];
      int egmax = eg[0];
      #pragma unroll
      for (int i = 1; i < 8; ++i) egmax = max(egmax, eg[i]);
      int egj = eg[0];
      #pragma unroll
      for (int i = 1; i < 8; ++i) if (j == i) egj = eg[i];
      float tb = sj * p2c(egj - egmax + 64);
      const float* gp = Gm + (dir * 8 + w) * 69 + j * 8;
      float p[8];
      #pragma unroll
      for (int i = 0; i < 8; ++i) p[i] = gp[i] * tb;
      #pragma unroll
      for (int m = 1; m <= 4; m <<= 1)
        #pragma unroll
        for (int i = 0; i < 8; ++i) p[i] += __shfl_xor(p[i], m);
      float mx = 0.f;
      #pragma unroll
      for (int i = 0; i < 8; ++i) mx = fmaxf(mx, p[i]);
      int e = fexp(mx); float sc = p2(-e);
      #pragma unroll
      for (int i = 0; i < 8; ++i) s[i] = p[i] * sc;
      Es += egmax + e - 64;
    }
  }
  __syncthreads();

  // level C: chunk-start vectors, written in PHYSICAL chunk order
  if (tid < 128) {
    const int dir = tid >> 6, lc = tid & 63, w = lc >> 3;
    float sg[8];
    #pragma unroll
    for (int b = 0; b < 8; ++b) sg[b] = Sg[(dir * 8 + w) * 9 + b];
    int Es = EsB[dir * 8 + w];
    int ep[8];
    #pragma unroll
    for (int b = 0; b < 8; ++b) ep[b] = sEP[(dir * 64 + lc) * 8 + b];
    int epmax = ep[0];
    #pragma unroll
    for (int b = 1; b < 8; ++b) epmax = max(epmax, ep[b]);
    float cs[8] = {0, 0, 0, 0, 0, 0, 0, 0};
    #pragma unroll
    for (int b = 0; b < 8; ++b) {
      float coef = sg[b] * p2c(ep[b] - epmax + 64);
      const float* pp = Pm + (dir * 64 + lc) * 64 + b * 8;
      float4 ca = *(const float4*)pp;
      float4 cb = *(const float4*)(pp + 4);
      cs[0] = fmaf(coef, ca.x, cs[0]); cs[1] = fmaf(coef, ca.y, cs[1]);
      cs[2] = fmaf(coef, ca.z, cs[2]); cs[3] = fmaf(coef, ca.w, cs[3]);
      cs[4] = fmaf(coef, cb.x, cs[4]); cs[5] = fmaf(coef, cb.y, cs[5]);
      cs[6] = fmaf(coef, cb.z, cs[6]); cs[7] = fmaf(coef, cb.w, cs[7]);
    }
    float mx = 0.f;
    #pragma unroll
    for (int i = 0; i < 8; ++i) mx = fmaxf(mx, cs[i]);
    int phys = dir ? (63 - lc) : lc;
    float* cp = Cs + (dir * 64 + phys) * 8;
    if (fexpbits(mx) == 0) {
      #pragma unroll
      for (int i = 0; i < 8; ++i) cp[i] = 0.f;
      Eacc[dir * 64 + phys] = NEGE;
    } else {
      int e = fexp(mx); float sc = p2(-e);
      #pragma unroll
      for (int i = 0; i < 8; ++i) cp[i] = cs[i] * sc;
      Eacc[dir * 64 + phys] = Es + epmax + e - 64;
    }
  }
}

// K3c: fp64 replay per chunk, fused with log -> writes aL/bL directly.
// 64-thread blocks => up to 256 VGPR, fp64 ring cannot spill.
__global__ __launch_bounds__(64) void k_replay(const float* __restrict__ M,
        const float* __restrict__ Cs, const int* __restrict__ Eacc,
        float* __restrict__ aL, float* __restrict__ bL) {
  const int dir = blockIdx.x;
  const int c = threadIdx.x;
  const int base = c * KCH;
  const float4* Mv = (const float4*)M;
  const float* cp = Cs + (dir * 64 + c) * 8;
  double st[8];
  #pragma unroll
  for (int i = 0; i < 8; ++i) st[i] = (double)cp[i];
  const double eacc = (double)Eacc[dir * 64 + c];
  if (dir == 0) {
    if (c == 0) aL[0] = 0.f;
    float4 ra = Mv[base * 2], rb = Mv[base * 2 + 1];
    for (int kg = 0; kg < 4; ++kg) {
      #pragma unroll
      for (int kk = 0; kk < 8; ++kk) {
        int k = kg * 8 + kk;
        float4 c0 = ra, c1 = rb;
        int nk = (k + 1 < KCH) ? k + 1 : KCH - 1;
        ra = Mv[(base + nk) * 2]; rb = Mv[(base + nk) * 2 + 1];
        double a_ = st[kk & 7];
        st[(kk + 1) & 7] = fma(a_, (double)c0.x, st[(kk + 1) & 7]);
        st[(kk + 2) & 7] = fma(a_, (double)c0.y, st[(kk + 2) & 7]);
        st[(kk + 3) & 7] = fma(a_, (double)c0.z, st[(kk + 3) & 7]);
        st[(kk + 4) & 7] = fma(a_, (double)c0.w, st[(kk + 4) & 7]);
        st[(kk + 5) & 7] = fma(a_, (double)c1.x, st[(kk + 5) & 7]);
        st[(kk + 6) & 7] = fma(a_, (double)c1.y, st[(kk + 6) & 7]);
        st[(kk + 7) & 7] = fma(a_, (double)c1.z, st[(kk + 7) & 7]);
        st[kk & 7]       = a_ * (double)c1.w;
        double val = st[(kk + 1) & 7];
        long long bits = __double_as_longlong(val);
        int e2 = (int)((bits >> 52) & 0x7ff) - 1023;
        double mant = __longlong_as_double((bits & 0xFFFFFFFFFFFFFLL) | 0x3FF0000000000000LL);
        float lg = log2f((float)mant);
        aL[base + k + 1] = (float)(((double)e2 + eacc + (double)lg) * LN2D);
      }
    }
  } else {
    if (c == 0) bL[TT] = 0.f;
    float4 ra = Mv[(base + KCH - 1) * 2], rb = Mv[(base + KCH - 1) * 2 + 1];
    for (int kg = 0; kg < 4; ++kg) {
      #pragma unroll
      for (int kk = 0; kk < 8; ++kk) {
        int k = kg * 8 + kk;
        int t = base + KCH - 1 - k;
        float4 c0 = ra, c1 = rb;
        int nk = (k + 1 < KCH) ? k + 1 : KCH - 1;
        int nt = base + KCH - 1 - nk;
        ra = Mv[nt * 2]; rb = Mv[nt * 2 + 1];
        double nb =            (double)c0.x * st[(8  - kk) & 7];
        nb = fma((double)c0.y, st[(9  - kk) & 7], nb);
        nb = fma((double)c0.z, st[(10 - kk) & 7], nb);
        nb = fma((double)c0.w, st[(11 - kk) & 7], nb);
        nb = fma((double)c1.x, st[(12 - kk) & 7], nb);
        nb = fma((double)c1.y, st[(13 - kk) & 7], nb);
        nb = fma((double)c1.z, st[(14 - kk) & 7], nb);
        nb = fma((double)c1.w, st[(15 - kk) & 7], nb);
        st[(7 - kk) & 7] = nb;
        long long bits = __double_as_longlong(nb);
        int e2 = (int)((bits >> 52) & 0x7ff) - 1023;
        double mant = __longlong_as_double((bits & 0xFFFFFFFFFFFFFLL) | 0x3FF0000000000000LL);
        float lg = log2f((float)mant);
        bL[t] = (float)(((double)e2 + eacc + (double)lg) * LN2D);
      }
    }
  }
}

// K4: dense output.
__global__ void k_out(const PK* __restrict__ pk, const unsigned long long* __restrict__ w64,
                      const float* __restrict__ aL, const float* __restrict__ bL,
                      float* __restrict__ out, int T, int V, int tPer) {
  int v = blockIdx.x * blockDim.x + threadIdx.x;
  PK p = pk[v];
  unsigned long long mask = (p.len >= 8) ? ~0ull : ((1ull << (8 * p.len)) - 1ull);
  unsigned long long key = p.key;
  float norm = aL[T];
  float base = p.logp - norm;
  int t0 = blockIdx.y * tPer;
  for (int t = t0; t < t0 + tPer; ++t) {
    unsigned long long w = w64[t];
    float val = 0.f;
    if (((w ^ key) & mask) == 0ull)
      val = __expf(aL[t] + base + bL[t + p.len]);
    out[(size_t)t * V + v] = val;
  }
}

extern "C" void kernel_launch(void* const* d_in, const int* in_sizes, int n_in,
                              void* d_out, int out_size, void* d_ws, size_t ws_size,
                              hipStream_t stream) {
  const int* seq    = (const int*)d_in[0];
  const int* pieces = (const int*)d_in[1];
  const int* plens  = (const int*)d_in[2];
  const float* logp = (const float*)d_in[3];
  float* out = (float*)d_out;
  const int T = in_sizes[0];
  const int V = in_sizes[2];

  char* p = (char*)d_ws;
  PK* pk = (PK*)p;                                   p += (size_t)V * sizeof(PK);
  unsigned long long* w64 = (unsigned long long*)p;  p += (size_t)T * 8;
  float* M = (float*)p;                              p += (size_t)T * LMAX * 4;
  float* Wt = (float*)p;                             p += (size_t)128 * 64 * 4;
  int* EWc = (int*)p;                                p += (size_t)128 * 8 * 4;
  float* Pm = (float*)p;                             p += (size_t)128 * 64 * 4;
  float* Cs = (float*)p;                             p += (size_t)128 * 8 * 4;
  int* Eacc = (int*)p;                               p += 512;
  float* aL = (float*)p;                             p += 8208;
  float* bL = (float*)p;                             p += 8208;

  int prepN = V + T + T * LMAX;
  k_prep<<<(prepN + 255) / 256, 256, 0, stream>>>(seq, pieces, plens, logp, pk, w64, M, T, V);

  const int tPer2 = 128;
  dim3 g2(V / 256, T / tPer2);
  k_match<<<g2, 256, 0, stream>>>(pk, w64, M, T, V, tPer2);

  k_chunks<<<2, 512, 0, stream>>>(M, Wt, EWc);
  k_combine<<<1, 256, 0, stream>>>(Wt, EWc, Pm, Cs, Eacc);
  k_replay<<<2, 64, 0, stream>>>(M, Cs, Eacc, aL, bL);

  const int tPer5 = 32;
  dim3 g5(V / 256, T / tPer5);
  k_out<<<g5, 256, 0, stream>>>(pk, w64, aL, bL, out, T, V, tPer5);
}

// Round 6
// 58.764 us; speedup vs baseline: 3.2467x; 1.0107x over previous
//
#include <hip/hip_runtime.h>
#include <stdint.h>

#define LMAX 8
#define KCH 32
#define NC  64
#define TT  2048
#define LN2D 0.6931471805599453
#define NEGE (-(1<<28))

struct __align__(16) PK { unsigned long long key; float logp; int len; };

__device__ __forceinline__ int fexp(float m) { return ((__float_as_int(m) >> 23) & 0xFF) - 127; }
__device__ __forceinline__ int fexpbits(float m) { return (__float_as_int(m) >> 23) & 0xFF; }
__device__ __forceinline__ float p2(int e) { return __int_as_float((e + 127) << 23); }
__device__ __forceinline__ float p2c(int e) { return (e < -126) ? 0.f : p2(e); }

// K1: pack pieces into 64-bit keys, pack sequence windows, zero M.
__global__ void k_prep(const int* __restrict__ seq, const int* __restrict__ pieces,
                       const int* __restrict__ plens, const float* __restrict__ logp,
                       PK* __restrict__ pk, unsigned long long* __restrict__ w64,
                       float* __restrict__ M, int T, int V) {
  int idx = blockIdx.x * blockDim.x + threadIdx.x;
  if (idx < V) {
    const int* pr = pieces + idx * LMAX;
    int len = plens[idx];
    unsigned long long key = 0ull;
    #pragma unroll
    for (int l = 0; l < LMAX; ++l) {
      unsigned long long b = (unsigned long long)(pr[l] & 0xFF);
      if (l < len) key |= b << (8 * l);
    }
    PK o; o.key = key; o.logp = logp[idx]; o.len = len;
    pk[idx] = o;
  } else if (idx < V + T) {
    int t = idx - V;
    unsigned long long w = 0ull;
    #pragma unroll
    for (int l = 0; l < LMAX; ++l) {
      int pos = t + l;
      unsigned long long b = (pos < T) ? (unsigned long long)(seq[pos] & 0xFF) : 0xFFull;
      w |= b << (8 * l);
    }
    w64[t] = w;
  } else if (idx < V + T + T * LMAX) {
    M[idx - V - T] = 0.f;
  }
}

// K2: M[t][len-1] += p_v for every matching (t,v).
__global__ void k_match(const PK* __restrict__ pk, const unsigned long long* __restrict__ w64,
                        float* __restrict__ M, int T, int V, int tPer) {
  int v = blockIdx.x * blockDim.x + threadIdx.x;
  PK p = pk[v];
  unsigned long long mask = (p.len >= 8) ? ~0ull : ((1ull << (8 * p.len)) - 1ull);
  unsigned long long key = p.key;
  int t0 = blockIdx.y * tPer;
  float prob = -1.f;
  for (int t = t0; t < t0 + tPer; ++t) {
    unsigned long long w = w64[t];
    if (((w ^ key) & mask) == 0ull) {
      if (prob < 0.f) prob = expf(p.logp);
      atomicAdd(&M[t * LMAX + (p.len - 1)], prob);
    }
  }
}

// K3 (fused): phase1 chunk matrices -> combine (levels A/B/C) -> fp64 replay+log.
// One block x 512 threads. Math is verbatim R4 (which passed); only the phase
// boundaries changed from kernel launches to __syncthreads().
__global__ __launch_bounds__(512, 2) void k_scan(const float* __restrict__ M,
        float* __restrict__ Wt, int* __restrict__ EWc, float* __restrict__ Pm,
        float* __restrict__ Cs, int* __restrict__ Eacc,
        float* __restrict__ aL, float* __restrict__ bL) {
  __shared__ float sWt[128][68];
  __shared__ int   sEW[128 * 8];
  __shared__ int   sEP[128 * 8];
  __shared__ float Gm[16 * 69];
  __shared__ float Sg[16 * 9];
  __shared__ int   EGs[16 * 8];
  __shared__ int   EsB[16];
  const int tid = threadIdx.x;
  const float4* Mv = (const float4*)M;

  // ---------- phase 1: chunk transfer-matrix columns ----------
  // Group g (8 lanes, lane b = basis col) evolves alpha chunk g (forward rows)
  // AND beta chunk g (backward rows) together; block-of-4-step dbuf prefetch.
  {
    const int g = tid >> 3, b = tid & 7;
    const int c = g;
    const int base = c * KCH;
    float va[8], vb[8];
    #pragma unroll
    for (int i = 0; i < 8; ++i) { va[i] = (i == b) ? 1.f : 0.f; vb[i] = va[i]; }
    int eca = 0, ecb = 0;
    float4 fa[8], bw[8], fn[8], bn[8];
    #pragma unroll
    for (int i = 0; i < 4; ++i) {
      fa[2 * i]     = Mv[(base + i) * 2];
      fa[2 * i + 1] = Mv[(base + i) * 2 + 1];
      bw[2 * i]     = Mv[(base + 31 - i) * 2];
      bw[2 * i + 1] = Mv[(base + 31 - i) * 2 + 1];
    }
    #pragma unroll
    for (int blk = 0; blk < 8; ++blk) {
      if (blk < 7) {
        #pragma unroll
        for (int i = 0; i < 4; ++i) {
          int rf = base + (blk + 1) * 4 + i;
          int rb = base + 31 - ((blk + 1) * 4 + i);
          fn[2 * i]     = Mv[rf * 2];
          fn[2 * i + 1] = Mv[rf * 2 + 1];
          bn[2 * i]     = Mv[rb * 2];
          bn[2 * i + 1] = Mv[rb * 2 + 1];
        }
      }
      #pragma unroll
      for (int s = 0; s < 4; ++s) {
        const int kk = blk * 4 + s;
        {  // alpha push-form step kk, row base+kk
          float4 c0 = fa[2 * s], c1 = fa[2 * s + 1];
          float a_ = va[kk & 7];
          va[(kk + 1) & 7] = fmaf(a_, c0.x, va[(kk + 1) & 7]);
          va[(kk + 2) & 7] = fmaf(a_, c0.y, va[(kk + 2) & 7]);
          va[(kk + 3) & 7] = fmaf(a_, c0.z, va[(kk + 3) & 7]);
          va[(kk + 4) & 7] = fmaf(a_, c0.w, va[(kk + 4) & 7]);
          va[(kk + 5) & 7] = fmaf(a_, c1.x, va[(kk + 5) & 7]);
          va[(kk + 6) & 7] = fmaf(a_, c1.y, va[(kk + 6) & 7]);
          va[(kk + 7) & 7] = fmaf(a_, c1.z, va[(kk + 7) & 7]);
          va[kk & 7]       = a_ * c1.w;
        }
        {  // beta window-form step kk, row base+31-kk
          float4 c0 = bw[2 * s], c1 = bw[2 * s + 1];
          float nb =      c0.x * vb[(8  - kk) & 7];
          nb = fmaf(c0.y, vb[(9  - kk) & 7], nb);
          nb = fmaf(c0.z, vb[(10 - kk) & 7], nb);
          nb = fmaf(c0.w, vb[(11 - kk) & 7], nb);
          nb = fmaf(c1.x, vb[(12 - kk) & 7], nb);
          nb = fmaf(c1.y, vb[(13 - kk) & 7], nb);
          nb = fmaf(c1.z, vb[(14 - kk) & 7], nb);
          nb = fmaf(c1.w, vb[(15 - kk) & 7], nb);
          vb[(7 - kk) & 7] = nb;
        }
      }
      {  // normalize both every 4 steps (R4 cadence)
        float mx = 0.f;
        #pragma unroll
        for (int i = 0; i < 8; ++i) mx = fmaxf(mx, va[i]);
        if (fexpbits(mx) != 0) {
          int e = fexp(mx); float sc = p2(-e);
          #pragma unroll
          for (int i = 0; i < 8; ++i) va[i] *= sc;
          eca += e;
        }
      }
      {
        float mx = 0.f;
        #pragma unroll
        for (int i = 0; i < 8; ++i) mx = fmaxf(mx, vb[i]);
        if (fexpbits(mx) != 0) {
          int e = fexp(mx); float sc = p2(-e);
          #pragma unroll
          for (int i = 0; i < 8; ++i) vb[i] *= sc;
          ecb += e;
        }
      }
      if (blk < 7) {
        #pragma unroll
        for (int i = 0; i < 8; ++i) { fa[i] = fn[i]; bw[i] = bn[i]; }
      }
    }
    {  // store dir 0 (logical index = c)
      float mx = 0.f;
      #pragma unroll
      for (int i = 0; i < 8; ++i) mx = fmaxf(mx, va[i]);
      float* wp = Wt + c * 64;
      if (fexpbits(mx) == 0) {
        #pragma unroll
        for (int i = 0; i < 8; ++i) wp[b * 8 + i] = 0.f;
        EWc[c * 8 + b] = NEGE;
      } else {
        int e = fexp(mx); float sc = p2(-e);
        #pragma unroll
        for (int i = 0; i < 8; ++i) wp[b * 8 + i] = va[i] * sc;
        EWc[c * 8 + b] = eca + e;
      }
    }
    {  // store dir 1 (logical index = 64 + (63-c))
      float mx = 0.f;
      #pragma unroll
      for (int i = 0; i < 8; ++i) mx = fmaxf(mx, vb[i]);
      int lt = 64 + (63 - c);
      float* wp = Wt + lt * 64;
      if (fexpbits(mx) == 0) {
        #pragma unroll
        for (int i = 0; i < 8; ++i) wp[b * 8 + i] = 0.f;
        EWc[lt * 8 + b] = NEGE;
      } else {
        int e = fexp(mx); float sc = p2(-e);
        #pragma unroll
        for (int i = 0; i < 8; ++i) wp[b * 8 + i] = vb[i] * sc;
        EWc[lt * 8 + b] = ecb + e;
      }
    }
  }
  __syncthreads();

  // ---------- stage Wt/EWc into LDS ----------
  for (int i = tid; i < 128 * 16; i += 512) {
    int task = i >> 4, q = i & 15;
    float4 v4 = ((const float4*)Wt)[i];
    *(float4*)&sWt[task][q * 4] = v4;
  }
  for (int i = tid; i < 1024; i += 512) sEW[i] = EWc[i];
  __syncthreads();

  // ---------- level A: basis through each group of 8 chunks ----------
  if (tid < 128) {
    const int dir = tid >> 6, w = (tid >> 3) & 7, b = tid & 7;
    float v[8];
    #pragma unroll
    for (int i = 0; i < 8; ++i) v[i] = (i == b) ? 1.f : 0.f;
    int ec = 0;
    for (int c = 0; c < 8; ++c) {
      int lc = w * 8 + c, lt = dir * 64 + lc;
      float* pp = Pm + lt * 64 + b * 8;
      #pragma unroll
      for (int i = 0; i < 8; ++i) pp[i] = v[i];
      sEP[lt * 8 + b] = ec;
      const float* wp = &sWt[lt][0];
      int ew[8];
      #pragma unroll
      for (int j = 0; j < 8; ++j) ew[j] = sEW[lt * 8 + j];
      int emax = ew[0];
      #pragma unroll
      for (int j = 1; j < 8; ++j) emax = max(emax, ew[j]);
      float nv[8] = {0, 0, 0, 0, 0, 0, 0, 0};
      #pragma unroll
      for (int j = 0; j < 8; ++j) {
        float tj = v[j] * p2c(ew[j] - emax + 64);
        float4 ca = *(const float4*)(wp + j * 8);
        float4 cb = *(const float4*)(wp + j * 8 + 4);
        nv[0] = fmaf(tj, ca.x, nv[0]); nv[1] = fmaf(tj, ca.y, nv[1]);
        nv[2] = fmaf(tj, ca.z, nv[2]); nv[3] = fmaf(tj, ca.w, nv[3]);
        nv[4] = fmaf(tj, cb.x, nv[4]); nv[5] = fmaf(tj, cb.y, nv[5]);
        nv[6] = fmaf(tj, cb.z, nv[6]); nv[7] = fmaf(tj, cb.w, nv[7]);
      }
      float mx = 0.f;
      #pragma unroll
      for (int i = 0; i < 8; ++i) mx = fmaxf(mx, nv[i]);
      if (fexpbits(mx) == 0) {
        #pragma unroll
        for (int i = 0; i < 8; ++i) v[i] = 0.f;
        ec = NEGE;
      } else {
        int e = fexp(mx); float sc = p2(-e);
        #pragma unroll
        for (int i = 0; i < 8; ++i) v[i] = nv[i] * sc;
        ec = ec + emax + e - 64;
      }
    }
    float* gp = Gm + (dir * 8 + w) * 69 + b * 8;
    #pragma unroll
    for (int i = 0; i < 8; ++i) gp[i] = v[i];
    EGs[(dir * 8 + w) * 8 + b] = ec;
  }
  __syncthreads();

  // ---------- level B: sequential over 8 groups (8 lanes per dir) ----------
  if (tid < 8 || (tid >= 64 && tid < 72)) {
    const int dir = (tid >= 64) ? 1 : 0, j = tid & 7;
    float s[8];
    #pragma unroll
    for (int i = 0; i < 8; ++i) s[i] = (i == 0) ? 1.f : 0.f;
    int Es = 0;
    for (int w = 0; w < 8; ++w) {
      float sj = s[0];
      #pragma unroll
      for (int i = 1; i < 8; ++i) if (j == i) sj = s[i];
      Sg[(dir * 8 + w) * 9 + j] = sj;
      if (j == 0) EsB[dir * 8 + w] = Es;
      int eg[8];
      #pragma unroll
      for (int i = 0; i < 8; ++i) eg[i] = EGs[(dir * 8 + w) * 8 + i];
      int egmax = eg[0];
      #pragma unroll
      for (int i = 1; i < 8; ++i) egmax = max(egmax, eg[i]);
      int egj = eg[0];
      #pragma unroll
      for (int i = 1; i < 8; ++i) if (j == i) egj = eg[i];
      float tb = sj * p2c(egj - egmax + 64);
      const float* gp = Gm + (dir * 8 + w) * 69 + j * 8;
      float p[8];
      #pragma unroll
      for (int i = 0; i < 8; ++i) p[i] = gp[i] * tb;
      #pragma unroll
      for (int m = 1; m <= 4; m <<= 1)
        #pragma unroll
        for (int i = 0; i < 8; ++i) p[i] += __shfl_xor(p[i], m);
      float mx = 0.f;
      #pragma unroll
      for (int i = 0; i < 8; ++i) mx = fmaxf(mx, p[i]);
      int e = fexp(mx); float sc = p2(-e);
      #pragma unroll
      for (int i = 0; i < 8; ++i) s[i] = p[i] * sc;
      Es += egmax + e - 64;
    }
  }
  __syncthreads();

  // ---------- level C: chunk-start vectors (physical order) ----------
  if (tid < 128) {
    const int dir = tid >> 6, lc = tid & 63, w = lc >> 3;
    float sg[8];
    #pragma unroll
    for (int b = 0; b < 8; ++b) sg[b] = Sg[(dir * 8 + w) * 9 + b];
    int Es = EsB[dir * 8 + w];
    int ep[8];
    #pragma unroll
    for (int b = 0; b < 8; ++b) ep[b] = sEP[(dir * 64 + lc) * 8 + b];
    int epmax = ep[0];
    #pragma unroll
    for (int b = 1; b < 8; ++b) epmax = max(epmax, ep[b]);
    float cs[8] = {0, 0, 0, 0, 0, 0, 0, 0};
    #pragma unroll
    for (int b = 0; b < 8; ++b) {
      float coef = sg[b] * p2c(ep[b] - epmax + 64);
      const float* pp = Pm + (dir * 64 + lc) * 64 + b * 8;
      float4 ca = *(const float4*)pp;
      float4 cb = *(const float4*)(pp + 4);
      cs[0] = fmaf(coef, ca.x, cs[0]); cs[1] = fmaf(coef, ca.y, cs[1]);
      cs[2] = fmaf(coef, ca.z, cs[2]); cs[3] = fmaf(coef, ca.w, cs[3]);
      cs[4] = fmaf(coef, cb.x, cs[4]); cs[5] = fmaf(coef, cb.y, cs[5]);
      cs[6] = fmaf(coef, cb.z, cs[6]); cs[7] = fmaf(coef, cb.w, cs[7]);
    }
    float mx = 0.f;
    #pragma unroll
    for (int i = 0; i < 8; ++i) mx = fmaxf(mx, cs[i]);
    int phys = dir ? (63 - lc) : lc;
    float* cp = Cs + (dir * 64 + phys) * 8;
    if (fexpbits(mx) == 0) {
      #pragma unroll
      for (int i = 0; i < 8; ++i) cp[i] = 0.f;
      Eacc[dir * 64 + phys] = NEGE;
    } else {
      int e = fexp(mx); float sc = p2(-e);
      #pragma unroll
      for (int i = 0; i < 8; ++i) cp[i] = cs[i] * sc;
      Eacc[dir * 64 + phys] = Es + epmax + e - 64;
    }
  }
  __syncthreads();

  // ---------- fp64 replay + log (R4 body, block-of-4 dbuf prefetch) ----------
  if (tid < 128) {
    const int dir = tid >> 6;
    const int c = tid & 63;
    const int base = c * KCH;
    const float* cp = Cs + (dir * 64 + c) * 8;
    double st[8];
    #pragma unroll
    for (int i = 0; i < 8; ++i) st[i] = (double)cp[i];
    const double eacc = (double)Eacc[dir * 64 + c];
    if (tid == 0) { aL[0] = 0.f; bL[TT] = 0.f; }
    float4 A[8], Bn[8];
    if (dir == 0) {
      #pragma unroll
      for (int i = 0; i < 4; ++i) {
        A[2 * i]     = Mv[(base + i) * 2];
        A[2 * i + 1] = Mv[(base + i) * 2 + 1];
      }
      #pragma unroll
      for (int blk = 0; blk < 8; ++blk) {
        if (blk < 7) {
          #pragma unroll
          for (int i = 0; i < 4; ++i) {
            int rf = base + (blk + 1) * 4 + i;
            Bn[2 * i]     = Mv[rf * 2];
            Bn[2 * i + 1] = Mv[rf * 2 + 1];
          }
        }
        #pragma unroll
        for (int s = 0; s < 4; ++s) {
          const int kk = blk * 4 + s;
          float4 c0 = A[2 * s], c1 = A[2 * s + 1];
          double a_ = st[kk & 7];
          st[(kk + 1) & 7] = fma(a_, (double)c0.x, st[(kk + 1) & 7]);
          st[(kk + 2) & 7] = fma(a_, (double)c0.y, st[(kk + 2) & 7]);
          st[(kk + 3) & 7] = fma(a_, (double)c0.z, st[(kk + 3) & 7]);
          st[(kk + 4) & 7] = fma(a_, (double)c0.w, st[(kk + 4) & 7]);
          st[(kk + 5) & 7] = fma(a_, (double)c1.x, st[(kk + 5) & 7]);
          st[(kk + 6) & 7] = fma(a_, (double)c1.y, st[(kk + 6) & 7]);
          st[(kk + 7) & 7] = fma(a_, (double)c1.z, st[(kk + 7) & 7]);
          st[kk & 7]       = a_ * (double)c1.w;
          double val = st[(kk + 1) & 7];
          long long bits = __double_as_longlong(val);
          int e2 = (int)((bits >> 52) & 0x7ff) - 1023;
          double mant = __longlong_as_double((bits & 0xFFFFFFFFFFFFFLL) | 0x3FF0000000000000LL);
          float lg = log2f((float)mant);
          aL[base + kk + 1] = (float)(((double)e2 + eacc + (double)lg) * LN2D);
        }
        if (blk < 7) {
          #pragma unroll
          for (int i = 0; i < 8; ++i) A[i] = Bn[i];
        }
      }
    } else {
      #pragma unroll
      for (int i = 0; i < 4; ++i) {
        A[2 * i]     = Mv[(base + 31 - i) * 2];
        A[2 * i + 1] = Mv[(base + 31 - i) * 2 + 1];
      }
      #pragma unroll
      for (int blk = 0; blk < 8; ++blk) {
        if (blk < 7) {
          #pragma unroll
          for (int i = 0; i < 4; ++i) {
            int rb = base + 31 - ((blk + 1) * 4 + i);
            Bn[2 * i]     = Mv[rb * 2];
            Bn[2 * i + 1] = Mv[rb * 2 + 1];
          }
        }
        #pragma unroll
        for (int s = 0; s < 4; ++s) {
          const int kk = blk * 4 + s;
          const int t = base + 31 - kk;
          float4 c0 = A[2 * s], c1 = A[2 * s + 1];
          double nb =            (double)c0.x * st[(8  - kk) & 7];
          nb = fma((double)c0.y, st[(9  - kk) & 7], nb);
          nb = fma((double)c0.z, st[(10 - kk) & 7], nb);
          nb = fma((double)c0.w, st[(11 - kk) & 7], nb);
          nb = fma((double)c1.x, st[(12 - kk) & 7], nb);
          nb = fma((double)c1.y, st[(13 - kk) & 7], nb);
          nb = fma((double)c1.z, st[(14 - kk) & 7], nb);
          nb = fma((double)c1.w, st[(15 - kk) & 7], nb);
          st[(7 - kk) & 7] = nb;
          long long bits = __double_as_longlong(nb);
          int e2 = (int)((bits >> 52) & 0x7ff) - 1023;
          double mant = __longlong_as_double((bits & 0xFFFFFFFFFFFFFLL) | 0x3FF0000000000000LL);
          float lg = log2f((float)mant);
          bL[t] = (float)(((double)e2 + eacc + (double)lg) * LN2D);
        }
        if (blk < 7) {
          #pragma unroll
          for (int i = 0; i < 8; ++i) A[i] = Bn[i];
        }
      }
    }
  }
}

// K4: dense output.
__global__ void k_out(const PK* __restrict__ pk, const unsigned long long* __restrict__ w64,
                      const float* __restrict__ aL, const float* __restrict__ bL,
                      float* __restrict__ out, int T, int V, int tPer) {
  int v = blockIdx.x * blockDim.x + threadIdx.x;
  PK p = pk[v];
  unsigned long long mask = (p.len >= 8) ? ~0ull : ((1ull << (8 * p.len)) - 1ull);
  unsigned long long key = p.key;
  float norm = aL[T];
  float base = p.logp - norm;
  int t0 = blockIdx.y * tPer;
  for (int t = t0; t < t0 + tPer; ++t) {
    unsigned long long w = w64[t];
    float val = 0.f;
    if (((w ^ key) & mask) == 0ull)
      val = __expf(aL[t] + base + bL[t + p.len]);
    out[(size_t)t * V + v] = val;
  }
}

extern "C" void kernel_launch(void* const* d_in, const int* in_sizes, int n_in,
                              void* d_out, int out_size, void* d_ws, size_t ws_size,
                              hipStream_t stream) {
  const int* seq    = (const int*)d_in[0];
  const int* pieces = (const int*)d_in[1];
  const int* plens  = (const int*)d_in[2];
  const float* logp = (const float*)d_in[3];
  float* out = (float*)d_out;
  const int T = in_sizes[0];
  const int V = in_sizes[2];

  char* p = (char*)d_ws;
  PK* pk = (PK*)p;                                   p += (size_t)V * sizeof(PK);
  unsigned long long* w64 = (unsigned long long*)p;  p += (size_t)T * 8;
  float* M = (float*)p;                              p += (size_t)T * LMAX * 4;
  float* Wt = (float*)p;                             p += (size_t)128 * 64 * 4;
  int* EWc = (int*)p;                                p += (size_t)128 * 8 * 4;
  float* Pm = (float*)p;                             p += (size_t)128 * 64 * 4;
  float* Cs = (float*)p;                             p += (size_t)128 * 8 * 4;
  int* Eacc = (int*)p;                               p += 512;
  float* aL = (float*)p;                             p += 8208;
  float* bL = (float*)p;                             p += 8208;

  int prepN = V + T + T * LMAX;
  k_prep<<<(prepN + 255) / 256, 256, 0, stream>>>(seq, pieces, plens, logp, pk, w64, M, T, V);

  const int tPer2 = 128;
  dim3 g2(V / 256, T / tPer2);
  k_match<<<g2, 256, 0, stream>>>(pk, w64, M, T, V, tPer2);

  k_scan<<<1, 512, 0, stream>>>(M, Wt, EWc, Pm, Cs, Eacc, aL, bL);

  const int tPer5 = 32;
  dim3 g5(V / 256, T / tPer5);
  k_out<<<g5, 256, 0, stream>>>(pk, w64, aL, bL, out, T, V, tPer5);
}